// Round 2
// baseline (153.553 us; speedup 1.0000x reference)
//
#include <hip/hip_runtime.h>
#include <cstdint>

#define B_ 8
#define N_ 512
#define D_ 256
#define E_ 16384

#define SBK 264   // sB row stride in halfwords (264*2 = 528 B, 16B-aligned rows)

using bf16x8 = __attribute__((ext_vector_type(8))) short;
using f32x4  = __attribute__((ext_vector_type(4))) float;

__device__ inline unsigned short f2bf(float f) {
    union { float f; unsigned u; } v; v.f = f;
    unsigned u = v.u;
    return (unsigned short)((u + 0x7fffu + ((u >> 16) & 1u)) >> 16);  // RNE
}

// 8 bf16 (u,v) pairs -> partial relu-dot (b1 already folded into u)
__device__ inline float dot8nb(uint4 qu, uint4 qv, const float* w2p) {
    unsigned us[4] = {qu.x, qu.y, qu.z, qu.w};
    unsigned vs[4] = {qv.x, qv.y, qv.z, qv.w};
    float p = 0.f;
#pragma unroll
    for (int j = 0; j < 4; j++) {
        float ulo = __uint_as_float(us[j] << 16);
        float uhi = __uint_as_float(us[j] & 0xffff0000u);
        float vlo = __uint_as_float(vs[j] << 16);
        float vhi = __uint_as_float(vs[j] & 0xffff0000u);
        float hlo = fmaxf(ulo + vlo, 0.f);
        float hhi = fmaxf(uhi + vhi, 0.f);
        p = fmaf(hlo, w2p[2 * j],     p);
        p = fmaf(hhi, w2p[2 * j + 1], p);
    }
    return p;
}

// Hand-rolled grid barrier (cnt/flag pre-zeroed by hipMemsetAsync each launch).
// Bounded spin: a residency failure yields a wrong answer + counters, not a hang.
__device__ inline void grid_barrier(int* cnt, int* flag) {
    __syncthreads();
    if (threadIdx.x == 0) {
        __threadfence();   // release all prior global writes (P, gBucket, gCount)
        int prev = __hip_atomic_fetch_add(cnt, 1, __ATOMIC_ACQ_REL,
                                          __HIP_MEMORY_SCOPE_AGENT);
        if (prev == (int)gridDim.x - 1) {
            __hip_atomic_store(flag, 1, __ATOMIC_RELEASE, __HIP_MEMORY_SCOPE_AGENT);
        } else {
            for (int it = 0; it < (1 << 16); ++it) {
                if (__hip_atomic_load(flag, __ATOMIC_ACQUIRE,
                                      __HIP_MEMORY_SCOPE_AGENT) != 0) break;
                __builtin_amdgcn_s_sleep(8);
            }
        }
        __threadfence();   // acquire: invalidate L1 so P/bucket reads are fresh
    }
    __syncthreads();
}

// Single regular kernel, 512 blocks x 256 threads, one grid barrier.
//   pre-barrier: blocks 0-7 LDS-histogram bucket scatter (gCount memset to 0);
//                ALL blocks: 64x64 MFMA GEMM tile of P = feat x [W1a|W1b]
//                (B-slice transposed global->LDS per block; A fragments read
//                directly from feat, no LDS, no per-k-step syncs; b1 folded
//                into U half at epilogue). bid&7 = batch = XCD -> batch-b P
//                slab lives in XCD b's L2.
//   barrier.
//   post-barrier: bucketed edge scoring; scores scattered into 8 LDS rows,
//                flushed as one contiguous 16 KB slab (no out pre-zeroing).
__global__ __launch_bounds__(256, 3)
void fused(const float* __restrict__ feat, const float* __restrict__ W1,
           const float* __restrict__ b1,   const float* __restrict__ W2,
           const float* __restrict__ b2,   const int* __restrict__ eidx,
           unsigned short* __restrict__ P,
           int* __restrict__ gCount, int* __restrict__ gBucket,
           int* __restrict__ gBar,   float* __restrict__ out)
{
    __shared__ __align__(16) char smem[33792];  // max(sB 33792, rows 16384, hist 4096)
    const int bid = blockIdx.x, t = threadIdx.x;
    const int b   = bid & 7;        // batch == XCD (bid%8 round-robin)
    const int loc = bid >> 3;       // 0..63
    const int m0  = b * 512 + (loc >> 3) * 64;   // P row base (8 m-tiles/batch)
    const int bn  = loc & 7;                     // n-tile (8 x 64 cols)
    const int n0  = bn * 64;

    // ---- bucket scatter: blocks 0-7, 2048 edges each (gCount pre-zeroed) ----
    if (bid < 8) {
        int* hist = (int*)smem;
        int* base = hist + 512;
        int mysrc[8], mydst[8], myslot[8];
        for (int i = t; i < 512; i += 256) hist[i] = 0;
        __syncthreads();
#pragma unroll
        for (int i = 0; i < 8; i++) {
            int e = bid * 2048 + i * 256 + t;
            mysrc[i] = eidx[e];
            mydst[i] = eidx[E_ + e];
            myslot[i] = atomicAdd(&hist[mysrc[i]], 1);
        }
        __syncthreads();
        for (int i = t; i < 512; i += 256) {
            int c = hist[i];
            base[i] = c ? atomicAdd(&gCount[i], c) : 0;
        }
        __syncthreads();
#pragma unroll
        for (int i = 0; i < 8; i++)
            gBucket[(mysrc[i] << 7) + base[mysrc[i]] + myslot[i]] = mydst[i];
        __syncthreads();   // smem reused below
    }

    // ---- GEMM: stage this block's B-slice (64 n x 256 k) transposed in LDS ----
    unsigned short* sB = (unsigned short*)smem;
    {
        const int h = bn >> 2, c0 = (bn & 3) * 64;  // W1 half + col base
        const int nn = t & 63, kg = t >> 6;          // col within tile, k-quarter
        const float* Wp = W1 + ((size_t)(h * 256 + kg * 64)) * 256 + c0 + nn;
        unsigned short* dstp = sB + nn * SBK + kg * 64;
#pragma unroll
        for (int o = 0; o < 8; o++) {
            union { bf16x8 v; unsigned short s[8]; } u;
#pragma unroll
            for (int j = 0; j < 8; j++)
                u.s[j] = f2bf(Wp[(size_t)(o * 8 + j) * 256]);
            *(bf16x8*)(dstp + o * 8) = u.v;
        }
    }
    __syncthreads();

    const int wave = t >> 6, lane = t & 63, l15 = lane & 15, quad = lane >> 4;
    {
        // A fragments straight from feat (row-major k-contiguous == MFMA A layout)
        const float* pAw = feat + (size_t)(m0 + wave * 16 + l15) * 256 + quad * 8;
        f32x4 acc[4];
#pragma unroll
        for (int cn = 0; cn < 4; cn++) acc[cn] = (f32x4){0.f, 0.f, 0.f, 0.f};
#pragma unroll
        for (int ks = 0; ks < 8; ks++) {
            float4 lo = *(const float4*)(pAw + ks * 32);
            float4 hi = *(const float4*)(pAw + ks * 32 + 4);
            union { bf16x8 v; unsigned short s[8]; } u;
            u.s[0] = f2bf(lo.x); u.s[1] = f2bf(lo.y); u.s[2] = f2bf(lo.z); u.s[3] = f2bf(lo.w);
            u.s[4] = f2bf(hi.x); u.s[5] = f2bf(hi.y); u.s[6] = f2bf(hi.z); u.s[7] = f2bf(hi.w);
            bf16x8 af = u.v;
#pragma unroll
            for (int cn = 0; cn < 4; cn++) {
                bf16x8 bfr = *(const bf16x8*)(sB + (cn * 16 + l15) * SBK + ks * 32 + quad * 8);
                acc[cn] = __builtin_amdgcn_mfma_f32_16x16x32_bf16(af, bfr, acc[cn], 0, 0, 0);
            }
        }
        // epilogue: P = bf16(acc + b1-fold on U half)
#pragma unroll
        for (int cn = 0; cn < 4; cn++) {
            int col = n0 + cn * 16 + l15;
            float bias = (col < 256) ? b1[col] : 0.f;
#pragma unroll
            for (int r = 0; r < 4; r++) {
                int row = m0 + wave * 16 + quad * 4 + r;
                P[(size_t)row * 512 + col] = f2bf(acc[cn][r] + bias);
            }
        }
    }

    grid_barrier(gBar, gBar + 32);

    // ---- edge scoring: 8 srcs/block, scores into LDS rows, one slab flush ----
    float* rows = (float*)smem;   // 8 x 512 floats
    {
        float4 z = make_float4(0.f, 0.f, 0.f, 0.f);
        float4* rz = (float4*)rows;
#pragma unroll
        for (int i = 0; i < 4; i++) rz[t + i * 256] = z;
    }
    __syncthreads();

    const int g = lane >> 4, w = lane & 15;
    const int wid = wave * 4 + g;              // 0..15 worker id
    float w2r[16];
#pragma unroll
    for (int j = 0; j < 4; j++)
        *(float4*)(w2r + 4 * j) = *(const float4*)(W2 + w * 16 + 4 * j);
    const float b2v = b2[0];

    const unsigned short* Pb = P + (size_t)b * 512 * 512;
    const unsigned short* Pv = Pb + 256 + w * 16;

#pragma unroll 1
    for (int jb = 0; jb < 4; jb++) {
        const int rl = jb * 2 + (wid >> 3);     // local row 0..7
        const int s  = loc * 8 + rl;            // bucket src
        const int o  = wid & 7;                 // worker offset in bucket

        const int en = gCount[s];
        const int* bucket = gBucket + (s << 7);

        const unsigned short* Pu = Pb + (size_t)s * 512 + w * 16;
        uint4 u0 = *(const uint4*)(Pu);
        uint4 u1 = *(const uint4*)(Pu + 8);
        float* rowp = rows + rl * 512;

        int j = o;
        int dst0 = 0; uint4 v00 = {}, v01 = {};
        if (j < en) {
            dst0 = bucket[j];
            const unsigned short* pv = Pv + (size_t)dst0 * 512;
            v00 = *(const uint4*)pv; v01 = *(const uint4*)(pv + 8);
        }
        while (j < en) {
            int jn = j + 8;
            int dst1 = 0; uint4 v10 = {}, v11 = {};
            if (jn < en) {
                dst1 = bucket[jn];
                const unsigned short* pv = Pv + (size_t)dst1 * 512;
                v10 = *(const uint4*)pv; v11 = *(const uint4*)(pv + 8);
            }
            float p = dot8nb(u0, v00, w2r) + dot8nb(u1, v01, w2r + 8);
            p += __shfl_xor(p, 1);
            p += __shfl_xor(p, 2);
            p += __shfl_xor(p, 4);
            p += __shfl_xor(p, 8);
            if (w == 0)
                rowp[dst0] = 1.0f / (1.0f + __expf(-(p + b2v)));
            dst0 = dst1; v00 = v10; v01 = v11; j = jn;
        }
    }
    __syncthreads();

    // flush 8 rows = 16 KB contiguous
    {
        float4* dstf = (float4*)(out + ((size_t)b * 512 + (size_t)loc * 8) * 512);
        const float4* srcf = (const float4*)rows;
#pragma unroll
        for (int i = 0; i < 4; i++) dstf[t + i * 256] = srcf[t + i * 256];
    }
}

extern "C" void kernel_launch(void* const* d_in, const int* in_sizes, int n_in,
                              void* d_out, int out_size, void* d_ws, size_t ws_size,
                              hipStream_t stream) {
    const float* feat = (const float*)d_in[0];
    const float* W1   = (const float*)d_in[1];
    const float* b1   = (const float*)d_in[2];
    const float* W2   = (const float*)d_in[3];
    const float* b2   = (const float*)d_in[4];
    const int*   eidx = (const int*)d_in[5];
    float* out = (float*)d_out;

    int* gCount  = (int*)d_ws;                                   // 2 KB
    int* gBar    = (int*)((char*)d_ws + 2048);                   // cnt@+0, flag@+128
    int* gBucket = (int*)((char*)d_ws + 4096);                   // 256 KB
    unsigned short* P = (unsigned short*)((char*)d_ws + (1 << 20)); // 4 MB

    hipMemsetAsync(d_ws, 0, 2560, stream);   // zero gCount + barrier state
    fused<<<dim3(512), dim3(256), 0, stream>>>(feat, W1, b1, W2, b2, eidx,
                                               P, gCount, gBucket, gBar, out);
}

// Round 3
// 92.046 us; speedup vs baseline: 1.6682x; 1.6682x over previous
//
#include <hip/hip_runtime.h>
#include <cstdint>

#define B_ 8
#define N_ 512
#define D_ 256
#define E_ 16384

#define SBK 264   // sB row stride in halfwords (264*2 = 528 B, 16B-aligned rows)
#define NBLK 512

using bf16x8 = __attribute__((ext_vector_type(8))) short;
using f32x4  = __attribute__((ext_vector_type(4))) float;

__device__ inline unsigned short f2bf(float f) {
    union { float f; unsigned u; } v; v.f = f;
    unsigned u = v.u;
    return (unsigned short)((u + 0x7fffu + ((u >> 16) & 1u)) >> 16);  // RNE
}

// 8 bf16 (u,v) pairs -> partial relu-dot (b1 already folded into u)
__device__ inline float dot8nb(uint4 qu, uint4 qv, const float* w2p) {
    unsigned us[4] = {qu.x, qu.y, qu.z, qu.w};
    unsigned vs[4] = {qv.x, qv.y, qv.z, qv.w};
    float p = 0.f;
#pragma unroll
    for (int j = 0; j < 4; j++) {
        float ulo = __uint_as_float(us[j] << 16);
        float uhi = __uint_as_float(us[j] & 0xffff0000u);
        float vlo = __uint_as_float(vs[j] << 16);
        float vhi = __uint_as_float(vs[j] & 0xffff0000u);
        float hlo = fmaxf(ulo + vlo, 0.f);
        float hhi = fmaxf(uhi + vhi, 0.f);
        p = fmaf(hlo, w2p[2 * j],     p);
        p = fmaf(hhi, w2p[2 * j + 1], p);
    }
    return p;
}

// Coherence-minimal grid barrier. All producer->consumer data (P, out-zero)
// is intra-XCD (bid&7 = batch = XCD), so NO L2 writeback/invalidate is needed:
//   release: s_waitcnt vmcnt(0) drains stores into the XCD L2 (vL1 is WT)
//   arrive/flag: RELAXED agent-scope atomics (sc1 -> coherence point), which
//   do NOT emit buffer_inv/buffer_wbl2 (the L2-nuking cost of round 2).
// Bounded spin: residency failure -> wrong answer + counters, not a hang.
__device__ inline void grid_barrier(int* cnt, int* flag) {
    __syncthreads();
    if (threadIdx.x == 0) {
        asm volatile("s_waitcnt vmcnt(0) lgkmcnt(0)" ::: "memory");
        int prev = __hip_atomic_fetch_add(cnt, 1, __ATOMIC_RELAXED,
                                          __HIP_MEMORY_SCOPE_AGENT);
        if (prev == NBLK - 1) {
            __hip_atomic_store(flag, 1, __ATOMIC_RELAXED, __HIP_MEMORY_SCOPE_AGENT);
        } else {
            for (int it = 0; it < (1 << 17); ++it) {
                if (__hip_atomic_load(flag, __ATOMIC_RELAXED,
                                      __HIP_MEMORY_SCOPE_AGENT) != 0) break;
                // freshness fallback: RMW always served at coherence point
                if ((it & 63) == 63 &&
                    __hip_atomic_fetch_add(flag, 0, __ATOMIC_RELAXED,
                                           __HIP_MEMORY_SCOPE_AGENT) != 0) break;
                __builtin_amdgcn_s_sleep(2);
            }
        }
        asm volatile("" ::: "memory");
    }
    __syncthreads();
}

// Single kernel, 512 blocks x 256 threads, one grid barrier, no buckets.
//   pre-barrier: stage this block's 256-edge slice (src,dst) into LDS;
//                zero own 16KB out slab; 64x64 MFMA GEMM tile of
//                P = feat x [W1a|W1b] (B transposed global->LDS, A fragments
//                straight from feat, b1 folded into U half). bid&7 = batch
//                = XCD -> P slab + out slab stay in one XCD's L2.
//   barrier (no cache maintenance).
//   post-barrier: stream edges from LDS; per edge load U[src],V[dst] rows
//                from L2-resident P with a 2-deep pipeline (addresses all
//                known locally -> no dependent-load chains); 16-lane dot,
//                sigmoid, direct 4B scatter into pre-zeroed out.
__global__ __launch_bounds__(256, 4)
void fused(const float* __restrict__ feat, const float* __restrict__ W1,
           const float* __restrict__ b1,   const float* __restrict__ W2,
           const float* __restrict__ b2,   const int* __restrict__ eidx,
           unsigned short* __restrict__ P, int* __restrict__ gBar,
           float* __restrict__ out)
{
    __shared__ __align__(16) char smem[35840];   // sB 33792 + edges 2048
    unsigned short* sB = (unsigned short*)smem;
    int* sES = (int*)(smem + 33792);             // 256 src
    int* sED = sES + 256;                        // 256 dst

    const int bid = blockIdx.x, t = threadIdx.x;
    const int b   = bid & 7;                     // batch == XCD
    const int loc = bid >> 3;                    // 0..63
    const int m0  = b * 512 + (loc >> 3) * 64;   // P row base (8 m-tiles/batch)
    const int bn  = loc & 7;                     // n-tile (8 x 64 cols)
    const int n0  = bn * 64;

    // ---- stage edge slice (256 edges) into LDS ----
    sES[t] = eidx[loc * 256 + t];
    sED[t] = eidx[E_ + loc * 256 + t];

    // ---- zero own out slab: batch b, rows loc*8 .. loc*8+7 (16 KB) ----
    {
        float4 z = make_float4(0.f, 0.f, 0.f, 0.f);
        float4* oz = (float4*)(out + ((size_t)b * 512 + (size_t)loc * 8) * 512) + t;
#pragma unroll
        for (int i = 0; i < 4; i++) oz[i * 256] = z;
    }

    // ---- GEMM: stage B-slice (64 n x 256 k) transposed in LDS ----
    {
        const int h = bn >> 2, c0 = (bn & 3) * 64;   // W1 half + col base
        const int nn = t & 63, kg = t >> 6;          // col in tile, k-quarter
        const float* Wp = W1 + ((size_t)(h * 256 + kg * 64)) * 256 + c0 + nn;
        unsigned short* dstp = sB + nn * SBK + kg * 64;
#pragma unroll
        for (int o = 0; o < 8; o++) {
            union { bf16x8 v; unsigned short s[8]; } u;
#pragma unroll
            for (int j = 0; j < 8; j++)
                u.s[j] = f2bf(Wp[(size_t)(o * 8 + j) * 256]);
            *(bf16x8*)(dstp + o * 8) = u.v;
        }
    }
    __syncthreads();

    const int wave = t >> 6, lane = t & 63, l15 = lane & 15, quad = lane >> 4;
    {
        // A fragments straight from feat (row-major k-contiguous == MFMA A layout)
        const float* pAw = feat + (size_t)(m0 + wave * 16 + l15) * 256 + quad * 8;
        f32x4 acc[4];
#pragma unroll
        for (int cn = 0; cn < 4; cn++) acc[cn] = (f32x4){0.f, 0.f, 0.f, 0.f};
#pragma unroll
        for (int ks = 0; ks < 8; ks++) {
            float4 lo = *(const float4*)(pAw + ks * 32);
            float4 hi = *(const float4*)(pAw + ks * 32 + 4);
            union { bf16x8 v; unsigned short s[8]; } u;
            u.s[0] = f2bf(lo.x); u.s[1] = f2bf(lo.y); u.s[2] = f2bf(lo.z); u.s[3] = f2bf(lo.w);
            u.s[4] = f2bf(hi.x); u.s[5] = f2bf(hi.y); u.s[6] = f2bf(hi.z); u.s[7] = f2bf(hi.w);
            bf16x8 af = u.v;
#pragma unroll
            for (int cn = 0; cn < 4; cn++) {
                bf16x8 bfr = *(const bf16x8*)(sB + (cn * 16 + l15) * SBK + ks * 32 + quad * 8);
                acc[cn] = __builtin_amdgcn_mfma_f32_16x16x32_bf16(af, bfr, acc[cn], 0, 0, 0);
            }
        }
        // epilogue: P = bf16(acc), b1 folded into U half
#pragma unroll
        for (int cn = 0; cn < 4; cn++) {
            int col = n0 + cn * 16 + l15;
            float bias = (col < 256) ? b1[col] : 0.f;
#pragma unroll
            for (int r = 0; r < 4; r++) {
                int row = m0 + wave * 16 + quad * 4 + r;
                P[(size_t)row * 512 + col] = f2bf(acc[cn][r] + bias);
            }
        }
    }

    grid_barrier(gBar, gBar + 32);

    // ---- edge scoring: 16 workers x 16 edges, 2-deep pipeline ----
    {
        const int g = lane >> 4, w = lane & 15;
        const int wid = wave * 4 + g;            // worker 0..15

        float w2r[16];
#pragma unroll
        for (int j = 0; j < 4; j++)
            *(float4*)(w2r + 4 * j) = *(const float4*)(W2 + w * 16 + 4 * j);
        const float b2v = b2[0];

        const unsigned short* Pb = P + (size_t)b * 512 * 512;
        float* outb = out + (size_t)b * 512 * 512;

        int e = wid;
        int s0 = sES[e], d0 = sED[e];
        const unsigned short* pu = Pb + (size_t)s0 * 512 + w * 16;
        const unsigned short* pv = Pb + (size_t)d0 * 512 + 256 + w * 16;
        uint4 u00 = *(const uint4*)pu, u01 = *(const uint4*)(pu + 8);
        uint4 v00 = *(const uint4*)pv, v01 = *(const uint4*)(pv + 8);

#pragma unroll 1
        for (int i = 0; i < 16; i++) {
            int en = e + 16;
            int s1 = 0, d1 = 0;
            uint4 u10 = {}, u11 = {}, v10 = {}, v11 = {};
            if (i < 15) {
                s1 = sES[en]; d1 = sED[en];
                const unsigned short* qu = Pb + (size_t)s1 * 512 + w * 16;
                const unsigned short* qv = Pb + (size_t)d1 * 512 + 256 + w * 16;
                u10 = *(const uint4*)qu; u11 = *(const uint4*)(qu + 8);
                v10 = *(const uint4*)qv; v11 = *(const uint4*)(qv + 8);
            }
            float p = dot8nb(u00, v00, w2r) + dot8nb(u01, v01, w2r + 8);
            p += __shfl_xor(p, 1);
            p += __shfl_xor(p, 2);
            p += __shfl_xor(p, 4);
            p += __shfl_xor(p, 8);
            if (w == 0)
                outb[(size_t)s0 * 512 + d0] = 1.0f / (1.0f + __expf(-(p + b2v)));
            s0 = s1; d0 = d1;
            u00 = u10; u01 = u11; v00 = v10; v01 = v11;
            e = en;
        }
    }
}

extern "C" void kernel_launch(void* const* d_in, const int* in_sizes, int n_in,
                              void* d_out, int out_size, void* d_ws, size_t ws_size,
                              hipStream_t stream) {
    const float* feat = (const float*)d_in[0];
    const float* W1   = (const float*)d_in[1];
    const float* b1   = (const float*)d_in[2];
    const float* W2   = (const float*)d_in[3];
    const float* b2   = (const float*)d_in[4];
    const int*   eidx = (const int*)d_in[5];
    float* out = (float*)d_out;

    int* gBar = (int*)d_ws;                                       // cnt@0, flag@128B
    unsigned short* P = (unsigned short*)((char*)d_ws + 4096);    // 4 MB

    hipMemsetAsync(d_ws, 0, 256, stream);   // zero barrier state
    fused<<<dim3(NBLK), dim3(256), 0, stream>>>(feat, W1, b1, W2, b2, eidx,
                                                P, gBar, out);
}

// Round 4
// 86.718 us; speedup vs baseline: 1.7707x; 1.0614x over previous
//
#include <hip/hip_runtime.h>
#include <cstdint>

#define B_ 8
#define N_ 512
#define D_ 256
#define E_ 16384

#define SBK 264   // sB row stride in halfwords (528 B rows, 16B-aligned)
#define EPB 128   // edges per block in edge_k

using bf16x8 = __attribute__((ext_vector_type(8))) short;
using f32x4  = __attribute__((ext_vector_type(4))) float;

__device__ inline unsigned short f2bf(float f) {
    union { float f; unsigned u; } v; v.f = f;
    unsigned u = v.u;
    return (unsigned short)((u + 0x7fffu + ((u >> 16) & 1u)) >> 16);  // RNE
}

// 8 bf16 (u,v) pairs -> partial relu-dot (b1 already folded into u)
__device__ inline float dot8nb(uint4 qu, uint4 qv, const float* w2p) {
    unsigned us[4] = {qu.x, qu.y, qu.z, qu.w};
    unsigned vs[4] = {qv.x, qv.y, qv.z, qv.w};
    float p = 0.f;
#pragma unroll
    for (int j = 0; j < 4; j++) {
        float ulo = __uint_as_float(us[j] << 16);
        float uhi = __uint_as_float(us[j] & 0xffff0000u);
        float vlo = __uint_as_float(vs[j] << 16);
        float vhi = __uint_as_float(vs[j] & 0xffff0000u);
        float hlo = fmaxf(ulo + vlo, 0.f);
        float hhi = fmaxf(uhi + vhi, 0.f);
        p = fmaf(hlo, w2p[2 * j],     p);
        p = fmaf(hhi, w2p[2 * j + 1], p);
    }
    return p;
}

// P = feat x [W1a|W1b] (bf16, b1 folded into U half) + out pre-zero.
// 1024 blocks: bid&7 = batch = XCD; loc>>4 = m-tile (64 rows), loc&15 =
// n-tile (32 cols). 16.9 KB LDS + launch_bounds(256,4) -> 4 blocks/CU,
// 16 waves/CU resident (2x round-3 TLP on the latency-exposed W1 loads).
__global__ __launch_bounds__(256, 4)
void gemm_k(const float* __restrict__ feat, const float* __restrict__ W1,
            const float* __restrict__ b1,   unsigned short* __restrict__ P,
            float* __restrict__ out)
{
    __shared__ __align__(16) unsigned short sB[32 * SBK];   // 16896 B

    const int bid = blockIdx.x, t = threadIdx.x;
    const int b   = bid & 7;                    // batch == XCD
    const int loc = bid >> 3;                   // 0..127
    const int m0  = b * 512 + (loc >> 4) * 64;  // P row base
    const int bn  = loc & 15;                   // n-tile (16 x 32 cols)
    const int n0  = bn * 32;

    // ---- B-stage: 32 n-cols x 256 k of W1, transposed into LDS ----
    {
        const int h = bn >> 3, c0 = (bn & 7) * 32;   // W1 half + col base
        const int col = t & 31, kg = t >> 5;          // col, 32-row k-group
        const float* Wp = W1 + ((size_t)(h * 256 + kg * 32)) * 256 + c0 + col;
        unsigned short* dstp = sB + col * SBK + kg * 32;
#pragma unroll
        for (int o = 0; o < 4; o++) {
            union { bf16x8 v; unsigned short s[8]; } u;
#pragma unroll
            for (int j = 0; j < 8; j++)
                u.s[j] = f2bf(Wp[(size_t)(o * 8 + j) * 256]);
            *(bf16x8*)(dstp + o * 8) = u.v;
        }
    }

    // ---- zero own out slab: batch b, rows loc*4 .. loc*4+3 (8 KB) ----
    {
        float4 z = make_float4(0.f, 0.f, 0.f, 0.f);
        float4* oz = (float4*)(out + ((size_t)b * 512 + (size_t)loc * 4) * 512) + t;
        oz[0] = z; oz[256] = z;
    }
    __syncthreads();

    const int wave = t >> 6, lane = t & 63, l15 = lane & 15, quad = lane >> 4;
    {
        // A fragments straight from feat (row-major k-contiguous == MFMA A layout)
        const float* pAw = feat + (size_t)(m0 + wave * 16 + l15) * 256 + quad * 8;
        f32x4 acc[2];
#pragma unroll
        for (int cn = 0; cn < 2; cn++) acc[cn] = (f32x4){0.f, 0.f, 0.f, 0.f};
#pragma unroll
        for (int ks = 0; ks < 8; ks++) {
            float4 lo = *(const float4*)(pAw + ks * 32);
            float4 hi = *(const float4*)(pAw + ks * 32 + 4);
            union { bf16x8 v; unsigned short s[8]; } u;
            u.s[0] = f2bf(lo.x); u.s[1] = f2bf(lo.y); u.s[2] = f2bf(lo.z); u.s[3] = f2bf(lo.w);
            u.s[4] = f2bf(hi.x); u.s[5] = f2bf(hi.y); u.s[6] = f2bf(hi.z); u.s[7] = f2bf(hi.w);
            bf16x8 af = u.v;
#pragma unroll
            for (int cn = 0; cn < 2; cn++) {
                bf16x8 bfr = *(const bf16x8*)(sB + (cn * 16 + l15) * SBK + ks * 32 + quad * 8);
                acc[cn] = __builtin_amdgcn_mfma_f32_16x16x32_bf16(af, bfr, acc[cn], 0, 0, 0);
            }
        }
        // epilogue: P = bf16(acc), b1 folded into U half
#pragma unroll
        for (int cn = 0; cn < 2; cn++) {
            int col = n0 + cn * 16 + l15;
            float bias = (col < 256) ? b1[col] : 0.f;
#pragma unroll
            for (int r = 0; r < 4; r++) {
                int row = m0 + wave * 16 + quad * 4 + r;
                P[(size_t)row * 512 + col] = f2bf(acc[cn][r] + bias);
            }
        }
    }
}

// Edge scoring: 1024 blocks x 128 edges; 16-lane workers, 8 edges each,
// 4-deep software pipeline (all addresses LDS-local -> no dependent loads,
// ~16 loads/lane outstanding). launch_bounds(256,4) -> 4 blocks/CU,
// 16 waves/CU (2x round-3 phase-2 TLP).
__global__ __launch_bounds__(256, 4)
void edge_k(const unsigned short* __restrict__ P, const float* __restrict__ W2,
            const float* __restrict__ b2, const int* __restrict__ eidx,
            float* __restrict__ out)
{
    __shared__ int sES[EPB], sED[EPB];
    const int bid = blockIdx.x, t = threadIdx.x;
    const int b = bid & 7, loc = bid >> 3;       // batch, edge-slice 0..127

    if (t < EPB) sES[t] = eidx[loc * EPB + t];
    else         sED[t - EPB] = eidx[E_ + loc * EPB + (t - EPB)];
    __syncthreads();

    const int lane = t & 63, wave = t >> 6;
    const int g = lane >> 4, w = lane & 15;
    const int wid = wave * 4 + g;                // worker 0..15
    const int e0 = wid * 8;

    float w2r[16];
#pragma unroll
    for (int j = 0; j < 4; j++)
        *(float4*)(w2r + 4 * j) = *(const float4*)(W2 + w * 16 + 4 * j);
    const float b2v = b2[0];

    const unsigned short* Pb = P + (size_t)b * 512 * 512;
    float* outb = out + (size_t)b * 512 * 512;

    uint4 u0[4], u1[4], v0[4], v1[4];
#pragma unroll
    for (int i = 0; i < 4; i++) {
        const unsigned short* pu = Pb + (size_t)sES[e0 + i] * 512 + w * 16;
        const unsigned short* pv = Pb + (size_t)sED[e0 + i] * 512 + 256 + w * 16;
        u0[i] = *(const uint4*)pu; u1[i] = *(const uint4*)(pu + 8);
        v0[i] = *(const uint4*)pv; v1[i] = *(const uint4*)(pv + 8);
    }
#pragma unroll
    for (int i = 0; i < 8; i++) {
        const int sl = i & 3;
        float p = dot8nb(u0[sl], v0[sl], w2r) + dot8nb(u1[sl], v1[sl], w2r + 8);
        if (i < 4) {  // refill freed slot with edge i+4 (3 iters of slack)
            const unsigned short* pu = Pb + (size_t)sES[e0 + i + 4] * 512 + w * 16;
            const unsigned short* pv = Pb + (size_t)sED[e0 + i + 4] * 512 + 256 + w * 16;
            u0[sl] = *(const uint4*)pu; u1[sl] = *(const uint4*)(pu + 8);
            v0[sl] = *(const uint4*)pv; v1[sl] = *(const uint4*)(pv + 8);
        }
        p += __shfl_xor(p, 1);
        p += __shfl_xor(p, 2);
        p += __shfl_xor(p, 4);
        p += __shfl_xor(p, 8);
        if (w == 0)
            outb[(size_t)sES[e0 + i] * 512 + sED[e0 + i]] =
                1.0f / (1.0f + __expf(-(p + b2v)));
    }
}

extern "C" void kernel_launch(void* const* d_in, const int* in_sizes, int n_in,
                              void* d_out, int out_size, void* d_ws, size_t ws_size,
                              hipStream_t stream) {
    const float* feat = (const float*)d_in[0];
    const float* W1   = (const float*)d_in[1];
    const float* b1   = (const float*)d_in[2];
    const float* W2   = (const float*)d_in[3];
    const float* b2   = (const float*)d_in[4];
    const int*   eidx = (const int*)d_in[5];
    float* out = (float*)d_out;

    unsigned short* P = (unsigned short*)d_ws;   // 4 MB

    gemm_k<<<dim3(1024), dim3(256), 0, stream>>>(feat, W1, b1, P, out);
    edge_k<<<dim3(1024), dim3(256), 0, stream>>>(P, W2, b2, eidx, out);
}

// Round 5
// 85.924 us; speedup vs baseline: 1.7871x; 1.0092x over previous
//
#include <hip/hip_runtime.h>
#include <cstdint>

#define B_ 8
#define N_ 512
#define D_ 256
#define E_ 16384

#define SBK 264   // sB row stride in halfwords (528 B rows, 16B-aligned)

using bf16x8 = __attribute__((ext_vector_type(8))) short;
using f32x4  = __attribute__((ext_vector_type(4))) float;
using f32x2  = __attribute__((ext_vector_type(2))) float;

__device__ inline unsigned short f2bf(float f) {
    union { float f; unsigned u; } v; v.f = f;
    unsigned u = v.u;
    return (unsigned short)((u + 0x7fffu + ((u >> 16) & 1u)) >> 16);  // RNE
}

// one bf16x2 dword pair of (u,v): relu(u+v) dot w-pair, packed f32x2 lanes
// (v_pk_add_f32 / v_pk_max / v_pk_fma_f32)
__device__ inline void pk_step(unsigned ud, unsigned vd, f32x2 wp, f32x2& acc) {
    f32x2 uu, vv;
    uu.x = __uint_as_float(ud << 16); uu.y = __uint_as_float(ud & 0xffff0000u);
    vv.x = __uint_as_float(vd << 16); vv.y = __uint_as_float(vd & 0xffff0000u);
    f32x2 s = uu + vv;
    s = __builtin_elementwise_max(s, (f32x2){0.f, 0.f});
    acc += s * wp;
}

__device__ inline float edge_dot(uint4 u0, uint4 u1, uint4 v0, uint4 v1,
                                 const f32x2* w2p) {
    f32x2 acc = {0.f, 0.f};
    pk_step(u0.x, v0.x, w2p[0], acc);
    pk_step(u0.y, v0.y, w2p[1], acc);
    pk_step(u0.z, v0.z, w2p[2], acc);
    pk_step(u0.w, v0.w, w2p[3], acc);
    pk_step(u1.x, v1.x, w2p[4], acc);
    pk_step(u1.y, v1.y, w2p[5], acc);
    pk_step(u1.z, v1.z, w2p[6], acc);
    pk_step(u1.w, v1.w, w2p[7], acc);
    return acc.x + acc.y;
}

// P = feat x [W1a|W1b] (bf16, b1 folded into U half) + out pre-zero.
// 1024 blocks: bid&7 = batch = XCD; loc>>4 = m-tile (64 rows), loc&15 =
// n-tile (32 cols). 16.9 KB LDS, 4 blocks/CU, 16 waves/CU. (unchanged R4)
__global__ __launch_bounds__(256, 4)
void gemm_k(const float* __restrict__ feat, const float* __restrict__ W1,
            const float* __restrict__ b1,   unsigned short* __restrict__ P,
            float* __restrict__ out)
{
    __shared__ __align__(16) unsigned short sB[32 * SBK];   // 16896 B

    const int bid = blockIdx.x, t = threadIdx.x;
    const int b   = bid & 7;                    // batch == XCD
    const int loc = bid >> 3;                   // 0..127
    const int m0  = b * 512 + (loc >> 4) * 64;  // P row base
    const int bn  = loc & 15;                   // n-tile (16 x 32 cols)
    const int n0  = bn * 32;

    // ---- B-stage: 32 n-cols x 256 k of W1, transposed into LDS ----
    {
        const int h = bn >> 3, c0 = (bn & 7) * 32;   // W1 half + col base
        const int col = t & 31, kg = t >> 5;          // col, 32-row k-group
        const float* Wp = W1 + ((size_t)(h * 256 + kg * 32)) * 256 + c0 + col;
        unsigned short* dstp = sB + col * SBK + kg * 32;
#pragma unroll
        for (int o = 0; o < 4; o++) {
            union { bf16x8 v; unsigned short s[8]; } u;
#pragma unroll
            for (int j = 0; j < 8; j++)
                u.s[j] = f2bf(Wp[(size_t)(o * 8 + j) * 256]);
            *(bf16x8*)(dstp + o * 8) = u.v;
        }
    }

    // ---- zero own out slab: batch b, rows loc*4 .. loc*4+3 (8 KB) ----
    {
        float4 z = make_float4(0.f, 0.f, 0.f, 0.f);
        float4* oz = (float4*)(out + ((size_t)b * 512 + (size_t)loc * 4) * 512) + t;
        oz[0] = z; oz[256] = z;
    }
    __syncthreads();

    const int wave = t >> 6, lane = t & 63, l15 = lane & 15, quad = lane >> 4;
    {
        // A fragments straight from feat (row-major k-contiguous == MFMA A layout)
        const float* pAw = feat + (size_t)(m0 + wave * 16 + l15) * 256 + quad * 8;
        f32x4 acc[2];
#pragma unroll
        for (int cn = 0; cn < 2; cn++) acc[cn] = (f32x4){0.f, 0.f, 0.f, 0.f};
#pragma unroll
        for (int ks = 0; ks < 8; ks++) {
            float4 lo = *(const float4*)(pAw + ks * 32);
            float4 hi = *(const float4*)(pAw + ks * 32 + 4);
            union { bf16x8 v; unsigned short s[8]; } u;
            u.s[0] = f2bf(lo.x); u.s[1] = f2bf(lo.y); u.s[2] = f2bf(lo.z); u.s[3] = f2bf(lo.w);
            u.s[4] = f2bf(hi.x); u.s[5] = f2bf(hi.y); u.s[6] = f2bf(hi.z); u.s[7] = f2bf(hi.w);
            bf16x8 af = u.v;
#pragma unroll
            for (int cn = 0; cn < 2; cn++) {
                bf16x8 bfr = *(const bf16x8*)(sB + (cn * 16 + l15) * SBK + ks * 32 + quad * 8);
                acc[cn] = __builtin_amdgcn_mfma_f32_16x16x32_bf16(af, bfr, acc[cn], 0, 0, 0);
            }
        }
        // epilogue: P = bf16(acc), b1 folded into U half
#pragma unroll
        for (int cn = 0; cn < 2; cn++) {
            int col = n0 + cn * 16 + l15;
            float bias = (col < 256) ? b1[col] : 0.f;
#pragma unroll
            for (int r = 0; r < 4; r++) {
                int row = m0 + wave * 16 + quad * 4 + r;
                P[(size_t)row * 512 + col] = f2bf(acc[cn][r] + bias);
            }
        }
    }
}

// Edge scoring: 2048 blocks x 64 edges; 16-lane workers own 4 edges and
// issue ALL 16 uint4 loads up-front (16 outstanding/lane from the start —
// no refill oscillation), then compute fully unrolled. Packed-f32 dot.
__global__ __launch_bounds__(256, 4)
void edge_k(const unsigned short* __restrict__ P, const float* __restrict__ W2,
            const float* __restrict__ b2, const int* __restrict__ eidx,
            float* __restrict__ out)
{
    __shared__ int sES[64], sED[64];
    const int bid = blockIdx.x, t = threadIdx.x;
    const int b = bid & 7, loc = bid >> 3;       // batch, edge-slice 0..255

    if (t < 64)        sES[t] = eidx[loc * 64 + t];
    else if (t < 128)  sED[t - 64] = eidx[E_ + loc * 64 + (t - 64)];
    __syncthreads();

    const int lane = t & 63, wave = t >> 6;
    const int g = lane >> 4, w = lane & 15;
    const int wid = wave * 4 + g;                // worker 0..15
    const int e0 = wid * 4;

    f32x2 w2p[8];
#pragma unroll
    for (int j = 0; j < 8; j++) {
        w2p[j].x = W2[w * 16 + 2 * j];
        w2p[j].y = W2[w * 16 + 2 * j + 1];
    }
    const float b2v = b2[0];

    const unsigned short* Pb = P + (size_t)b * 512 * 512;
    float* outb = out + (size_t)b * 512 * 512;

    int ss[4], dd[4];
    uint4 u0[4], u1[4], v0[4], v1[4];
#pragma unroll
    for (int i = 0; i < 4; i++) {
        ss[i] = sES[e0 + i]; dd[i] = sED[e0 + i];
        const unsigned short* pu = Pb + (size_t)ss[i] * 512 + w * 16;
        const unsigned short* pv = Pb + (size_t)dd[i] * 512 + 256 + w * 16;
        u0[i] = *(const uint4*)pu; u1[i] = *(const uint4*)(pu + 8);
        v0[i] = *(const uint4*)pv; v1[i] = *(const uint4*)(pv + 8);
    }
#pragma unroll
    for (int i = 0; i < 4; i++) {
        float p = edge_dot(u0[i], u1[i], v0[i], v1[i], w2p);
        p += __shfl_xor(p, 1);
        p += __shfl_xor(p, 2);
        p += __shfl_xor(p, 4);
        p += __shfl_xor(p, 8);
        if (w == 0)
            outb[(size_t)ss[i] * 512 + dd[i]] = 1.0f / (1.0f + __expf(-(p + b2v)));
    }
}

extern "C" void kernel_launch(void* const* d_in, const int* in_sizes, int n_in,
                              void* d_out, int out_size, void* d_ws, size_t ws_size,
                              hipStream_t stream) {
    const float* feat = (const float*)d_in[0];
    const float* W1   = (const float*)d_in[1];
    const float* b1   = (const float*)d_in[2];
    const float* W2   = (const float*)d_in[3];
    const float* b2   = (const float*)d_in[4];
    const int*   eidx = (const int*)d_in[5];
    float* out = (float*)d_out;

    unsigned short* P = (unsigned short*)d_ws;   // 4 MB

    gemm_k<<<dim3(1024), dim3(256), 0, stream>>>(feat, W1, b1, P, out);
    edge_k<<<dim3(2048), dim3(256), 0, stream>>>(P, W2, b2, eidx, out);
}